// Round 1
// baseline (1869.618 us; speedup 1.0000x reference)
//
#include <hip/hip_runtime.h>
#include <hip/hip_bf16.h>

#define N_TOK 8192
#define HD    2048
#define NE    8
#define FF    1024

using f32x4  = __attribute__((ext_vector_type(4))) float;
using bf16x8 = __attribute__((ext_vector_type(8))) __bf16;

__device__ __forceinline__ unsigned short f2bf(float f) {
  unsigned u = __float_as_uint(f);
  u += 0x7FFFu + ((u >> 16) & 1u);   // RTNE (inputs are finite/normal)
  return (unsigned short)(u >> 16);
}

__device__ __forceinline__ void gl_lds16(const void* g, void* l) {
  __builtin_amdgcn_global_load_lds((__attribute__((address_space(1))) void*)g,
                                   (__attribute__((address_space(3))) void*)l,
                                   16, 0, 0);
}

// ---- elementwise fp32 -> bf16 convert (vectorized) ----
__global__ void k_conv(const float* __restrict__ in, unsigned short* __restrict__ out, int n4) {
  int stride = gridDim.x * blockDim.x;
  for (int i = blockIdx.x * blockDim.x + threadIdx.x; i < n4; i += stride) {
    float4 v = reinterpret_cast<const float4*>(in)[i];
    ushort4 o;
    o.x = f2bf(v.x); o.y = f2bf(v.y); o.z = f2bf(v.z); o.w = f2bf(v.w);
    reinterpret_cast<ushort4*>(out)[i] = o;
  }
}

// ---- tiled transpose + convert: in[z][R][C] fp32 -> out[z*out_z + c*ostride + r] bf16 ----
__global__ void k_tconv(const float* __restrict__ in, unsigned short* __restrict__ out,
                        int R, int C, size_t in_z, size_t out_z, size_t ostride) {
  __shared__ float tile[32][33];
  const int z = blockIdx.z;
  const int c0 = blockIdx.x * 32, r0 = blockIdx.y * 32;
  const int tx = threadIdx.x, ty = threadIdx.y;
  const float* ip = in + (size_t)z * in_z;
  unsigned short* op = out + (size_t)z * out_z;
  #pragma unroll
  for (int i = ty; i < 32; i += 8)
    tile[i][tx] = ip[(size_t)(r0 + i) * C + (c0 + tx)];
  __syncthreads();
  #pragma unroll
  for (int i = ty; i < 32; i += 8)
    op[(size_t)(c0 + i) * ostride + (r0 + tx)] = f2bf(tile[tx][i]);
}

// ---- router: w = relu(x @ W_router), fp32 exact. one wave per token ----
__global__ void k_router(const float* __restrict__ x, const float* __restrict__ Wr,
                         float* __restrict__ w, float* __restrict__ rout) {
  const int lane = threadIdx.x & 63, wv = threadIdx.x >> 6;
  const int n = blockIdx.x * 4 + wv;
  const float* xr = x + (size_t)n * HD + lane * 32;
  const float* wbase = Wr + (size_t)lane * 32 * NE;
  float acc[8];
  #pragma unroll
  for (int e = 0; e < 8; ++e) acc[e] = 0.f;
  #pragma unroll
  for (int kk = 0; kk < 32; kk += 4) {
    float4 xv = *reinterpret_cast<const float4*>(xr + kk);
    #pragma unroll
    for (int t = 0; t < 4; ++t) {
      const float* wrow = wbase + (kk + t) * 8;
      float4 w0 = *reinterpret_cast<const float4*>(wrow);
      float4 w1 = *reinterpret_cast<const float4*>(wrow + 4);
      float xs = (t == 0) ? xv.x : (t == 1) ? xv.y : (t == 2) ? xv.z : xv.w;
      acc[0] += xs * w0.x; acc[1] += xs * w0.y; acc[2] += xs * w0.z; acc[3] += xs * w0.w;
      acc[4] += xs * w1.x; acc[5] += xs * w1.y; acc[6] += xs * w1.z; acc[7] += xs * w1.w;
    }
  }
  #pragma unroll
  for (int off = 32; off; off >>= 1) {
    #pragma unroll
    for (int e = 0; e < 8; ++e) acc[e] += __shfl_down(acc[e], off);
  }
  if (lane == 0) {
    #pragma unroll
    for (int e = 0; e < 8; ++e) {
      float v = acc[e] > 0.f ? acc[e] : 0.f;
      w[n * 8 + e] = v;
      rout[n * 8 + e] = v;
    }
  }
}

// ---- GEMM1: fused gate+up, epilogue silu(g)*u*w -> A2 (bf16) ----
// xb [N][H] bf16, Wg/Wu [E][F][H] bf16 (B^T layout). A2 row stride k2g, col block eloc*FF.
__global__ void __launch_bounds__(256) k_gemm1(
    const unsigned short* __restrict__ xb,
    const unsigned short* __restrict__ Wg,
    const unsigned short* __restrict__ Wu,
    const float* __restrict__ w,
    unsigned short* __restrict__ A2,
    int e0, int k2g) {
  __shared__ char lds[24576];
  char* As = lds;
  char* Bg = lds + 8192;
  char* Bu = lds + 16384;
  const int tid = threadIdx.x;
  const int lane = tid & 63, wv = tid >> 6;
  const int eloc = blockIdx.z;
  const int e = e0 + eloc;
  const int bm = blockIdx.y * 128;
  const int bf = blockIdx.x * 128;
  const int wr = wv >> 1, wc = wv & 1;

  const unsigned short* gA  = xb + (size_t)bm * HD;
  const unsigned short* gBg = Wg + ((size_t)e * FF + bf) * HD;
  const unsigned short* gBu = Wu + ((size_t)e * FF + bf) * HD;

  f32x4 zero = {0.f, 0.f, 0.f, 0.f};
  f32x4 accg[4][4], accu[4][4];
  #pragma unroll
  for (int i = 0; i < 4; ++i) {
    #pragma unroll
    for (int j = 0; j < 4; ++j) { accg[i][j] = zero; accu[i][j] = zero; }
  }

  const int srow = lane >> 2;          // staging row within 16-row group
  const int sch  = (lane & 3) * 8;     // staging k-chunk (elements)
  const int fr   = lane & 15;          // fragment row/col
  const int kb   = (lane >> 4) * 16;   // fragment k-group byte offset

  for (int k0 = 0; k0 < HD; k0 += 32) {
    #pragma unroll
    for (int r = 0; r < 2; ++r) {
      int row = r * 64 + wv * 16 + srow;
      char* ldst = (char*)0 + r * 4096 + wv * 1024;  // byte offset
      gl_lds16(gA  + (size_t)row * HD + k0 + sch, As + (size_t)(r * 4096 + wv * 1024));
      gl_lds16(gBg + (size_t)row * HD + k0 + sch, Bg + (size_t)(r * 4096 + wv * 1024));
      gl_lds16(gBu + (size_t)row * HD + k0 + sch, Bu + (size_t)(r * 4096 + wv * 1024));
      (void)ldst;
    }
    __syncthreads();
    bf16x8 a[4];
    #pragma unroll
    for (int i = 0; i < 4; ++i)
      a[i] = *(const bf16x8*)(As + (wr * 64 + i * 16 + fr) * 64 + kb);
    #pragma unroll
    for (int j = 0; j < 4; ++j) {
      bf16x8 bg = *(const bf16x8*)(Bg + (wc * 64 + j * 16 + fr) * 64 + kb);
      bf16x8 bu = *(const bf16x8*)(Bu + (wc * 64 + j * 16 + fr) * 64 + kb);
      #pragma unroll
      for (int i = 0; i < 4; ++i) {
        accg[i][j] = __builtin_amdgcn_mfma_f32_16x16x32_bf16(a[i], bg, accg[i][j], 0, 0, 0);
        accu[i][j] = __builtin_amdgcn_mfma_f32_16x16x32_bf16(a[i], bu, accu[i][j], 0, 0, 0);
      }
    }
    __syncthreads();
  }

  const int lrow = (lane >> 4) * 4;
  const int lcol = lane & 15;
  #pragma unroll
  for (int i = 0; i < 4; ++i) {
    #pragma unroll
    for (int r = 0; r < 4; ++r) {
      int n = bm + wr * 64 + i * 16 + lrow + r;
      float wn = w[n * 8 + e];
      size_t obase = (size_t)n * k2g + (size_t)eloc * FF + bf + wc * 64 + lcol;
      #pragma unroll
      for (int j = 0; j < 4; ++j) {
        float g = accg[i][j][r];
        float u = accu[i][j][r];
        float s = g / (1.f + __expf(-g));
        A2[obase + j * 16] = f2bf(s * u * wn);
      }
    }
  }
}

// ---- GEMM2: out(+)= A2 @ Wd^T-layout. A2 [N][k2g] bf16, Wd [H][NE*FF] bf16 (pre-offset) ----
__global__ void __launch_bounds__(256) k_gemm2(
    const unsigned short* __restrict__ A2,
    const unsigned short* __restrict__ Wd,
    float* __restrict__ out,
    int k2g, int accum) {
  __shared__ char lds[16384];
  char* As = lds;
  char* Bs = lds + 8192;
  const int tid = threadIdx.x;
  const int lane = tid & 63, wv = tid >> 6;
  const int bm = blockIdx.y * 128;
  const int bn = blockIdx.x * 128;
  const int wr = wv >> 1, wc = wv & 1;

  const unsigned short* gA = A2 + (size_t)bm * k2g;
  const unsigned short* gB = Wd + (size_t)bn * (NE * FF);

  f32x4 zero = {0.f, 0.f, 0.f, 0.f};
  f32x4 acc[4][4];
  #pragma unroll
  for (int i = 0; i < 4; ++i) {
    #pragma unroll
    for (int j = 0; j < 4; ++j) acc[i][j] = zero;
  }

  const int srow = lane >> 2;
  const int sch  = (lane & 3) * 8;
  const int fr   = lane & 15;
  const int kb   = (lane >> 4) * 16;

  for (int k0 = 0; k0 < k2g; k0 += 32) {
    #pragma unroll
    for (int r = 0; r < 2; ++r) {
      int row = r * 64 + wv * 16 + srow;
      gl_lds16(gA + (size_t)row * k2g + k0 + sch,        As + (size_t)(r * 4096 + wv * 1024));
      gl_lds16(gB + (size_t)row * (NE * FF) + k0 + sch,  Bs + (size_t)(r * 4096 + wv * 1024));
    }
    __syncthreads();
    bf16x8 a[4];
    #pragma unroll
    for (int i = 0; i < 4; ++i)
      a[i] = *(const bf16x8*)(As + (wr * 64 + i * 16 + fr) * 64 + kb);
    #pragma unroll
    for (int j = 0; j < 4; ++j) {
      bf16x8 b = *(const bf16x8*)(Bs + (wc * 64 + j * 16 + fr) * 64 + kb);
      #pragma unroll
      for (int i = 0; i < 4; ++i)
        acc[i][j] = __builtin_amdgcn_mfma_f32_16x16x32_bf16(a[i], b, acc[i][j], 0, 0, 0);
    }
    __syncthreads();
  }

  const int lrow = (lane >> 4) * 4;
  const int lcol = lane & 15;
  #pragma unroll
  for (int i = 0; i < 4; ++i) {
    #pragma unroll
    for (int r = 0; r < 4; ++r) {
      int n = bm + wr * 64 + i * 16 + lrow + r;
      float* op = out + (size_t)n * HD + bn + wc * 64 + lcol;
      #pragma unroll
      for (int j = 0; j < 4; ++j) {
        float v = acc[i][j][r];
        op[j * 16] = accum ? (op[j * 16] + v) : v;
      }
    }
  }
}

extern "C" void kernel_launch(void* const* d_in, const int* in_sizes, int n_in,
                              void* d_out, int out_size, void* d_ws, size_t ws_size,
                              hipStream_t stream) {
  (void)in_sizes; (void)out_size;
  if (n_in < 5) return;
  const float* x  = (const float*)d_in[0];
  const float* Wr = (const float*)d_in[1];
  const float* Wg = (const float*)d_in[2];
  const float* Wu = (const float*)d_in[3];
  const float* Wd = (const float*)d_in[4];
  float* out  = (float*)d_out;
  float* rout = out + (size_t)N_TOK * HD;

  char* ws = (char*)d_ws;
  const size_t SZ_XB = (size_t)N_TOK * HD * 2;      // 33,554,432 B
  const size_t SZ_W  = (size_t)NE * HD * FF * 2;    // 33,554,432 B each
  unsigned short* xb    = (unsigned short*)(ws);
  unsigned short* Wg_bt = (unsigned short*)(ws + SZ_XB);
  unsigned short* Wu_bt = (unsigned short*)(ws + SZ_XB + SZ_W);
  unsigned short* Wd_bt = (unsigned short*)(ws + SZ_XB + 2 * SZ_W);
  float*          wbuf  = (float*)(ws + SZ_XB + 3 * SZ_W);
  const size_t fixed = SZ_XB + 3 * SZ_W + (size_t)N_TOK * NE * 4;  // 134,479,872 B
  unsigned short* A2    = (unsigned short*)(ws + fixed);

  const size_t perE = (size_t)N_TOK * FF * 2;       // 16,777,216 B per expert slab
  int G = 8;
  while (G > 1 && fixed + (size_t)G * perE > ws_size) G >>= 1;

  // conversions
  k_conv<<<4096, 256, 0, stream>>>(x, xb, (N_TOK * HD) / 4);
  dim3 tb(32, 8);
  k_tconv<<<dim3(FF / 32, HD / 32, NE), tb, 0, stream>>>(
      Wg, Wg_bt, HD, FF, (size_t)HD * FF, (size_t)FF * HD, (size_t)HD);
  k_tconv<<<dim3(FF / 32, HD / 32, NE), tb, 0, stream>>>(
      Wu, Wu_bt, HD, FF, (size_t)HD * FF, (size_t)FF * HD, (size_t)HD);
  k_tconv<<<dim3(HD / 32, FF / 32, NE), tb, 0, stream>>>(
      Wd, Wd_bt, FF, HD, (size_t)FF * HD, (size_t)FF, (size_t)(NE * FF));

  // router (fp32 exact) -> wbuf + d_out router section
  k_router<<<N_TOK / 4, 256, 0, stream>>>(x, Wr, wbuf, rout);

  // expert GEMMs (G experts per pass; accumulate across passes)
  const int k2g = G * FF;
  for (int e0 = 0; e0 < NE; e0 += G) {
    k_gemm1<<<dim3(FF / 128, N_TOK / 128, G), 256, 0, stream>>>(
        xb, Wg_bt, Wu_bt, wbuf, A2, e0, k2g);
    k_gemm2<<<dim3(HD / 128, N_TOK / 128), 256, 0, stream>>>(
        A2, Wd_bt + (size_t)e0 * FF, out, k2g, e0 != 0);
  }
}

// Round 2
// 1287.438 us; speedup vs baseline: 1.4522x; 1.4522x over previous
//
#include <hip/hip_runtime.h>
#include <hip/hip_bf16.h>

#define N_TOK 8192
#define HD    2048
#define NE    8
#define FF    1024

using f32x4  = __attribute__((ext_vector_type(4))) float;
using bf16x8 = __attribute__((ext_vector_type(8))) __bf16;

__device__ __forceinline__ unsigned short f2bf(float f) {
  unsigned u = __float_as_uint(f);
  u += 0x7FFFu + ((u >> 16) & 1u);   // RTNE (inputs are finite/normal)
  return (unsigned short)(u >> 16);
}

__device__ __forceinline__ void gl_lds16(const void* g, void* l) {
  __builtin_amdgcn_global_load_lds((__attribute__((address_space(1))) void*)g,
                                   (__attribute__((address_space(3))) void*)l,
                                   16, 0, 0);
}

// ---- elementwise fp32 -> bf16 convert (vectorized) ----
__global__ void k_conv(const float* __restrict__ in, unsigned short* __restrict__ out, int n4) {
  int stride = gridDim.x * blockDim.x;
  for (int i = blockIdx.x * blockDim.x + threadIdx.x; i < n4; i += stride) {
    float4 v = reinterpret_cast<const float4*>(in)[i];
    ushort4 o;
    o.x = f2bf(v.x); o.y = f2bf(v.y); o.z = f2bf(v.z); o.w = f2bf(v.w);
    reinterpret_cast<ushort4*>(out)[i] = o;
  }
}

// ---- tiled transpose + convert: in[z][R][C] fp32 -> out[z*out_z + c*ostride + r] bf16 ----
__global__ void k_tconv(const float* __restrict__ in, unsigned short* __restrict__ out,
                        int R, int C, size_t in_z, size_t out_z, size_t ostride) {
  __shared__ float tile[32][33];
  const int z = blockIdx.z;
  const int c0 = blockIdx.x * 32, r0 = blockIdx.y * 32;
  const int tx = threadIdx.x, ty = threadIdx.y;
  const float* ip = in + (size_t)z * in_z;
  unsigned short* op = out + (size_t)z * out_z;
  #pragma unroll
  for (int i = ty; i < 32; i += 8)
    tile[i][tx] = ip[(size_t)(r0 + i) * C + (c0 + tx)];
  __syncthreads();
  #pragma unroll
  for (int i = ty; i < 32; i += 8)
    op[(size_t)(c0 + i) * ostride + (r0 + tx)] = f2bf(tile[tx][i]);
}

// ---- router: w = relu(x @ W_router), fp32 exact. one wave per token ----
__global__ void k_router(const float* __restrict__ x, const float* __restrict__ Wr,
                         float* __restrict__ w, float* __restrict__ rout) {
  const int lane = threadIdx.x & 63, wv = threadIdx.x >> 6;
  const int n = blockIdx.x * 4 + wv;
  const float* xr = x + (size_t)n * HD + lane * 32;
  const float* wbase = Wr + (size_t)lane * 32 * NE;
  float acc[8];
  #pragma unroll
  for (int e = 0; e < 8; ++e) acc[e] = 0.f;
  #pragma unroll
  for (int kk = 0; kk < 32; kk += 4) {
    float4 xv = *reinterpret_cast<const float4*>(xr + kk);
    #pragma unroll
    for (int t = 0; t < 4; ++t) {
      const float* wrow = wbase + (kk + t) * 8;
      float4 w0 = *reinterpret_cast<const float4*>(wrow);
      float4 w1 = *reinterpret_cast<const float4*>(wrow + 4);
      float xs = (t == 0) ? xv.x : (t == 1) ? xv.y : (t == 2) ? xv.z : xv.w;
      acc[0] += xs * w0.x; acc[1] += xs * w0.y; acc[2] += xs * w0.z; acc[3] += xs * w0.w;
      acc[4] += xs * w1.x; acc[5] += xs * w1.y; acc[6] += xs * w1.z; acc[7] += xs * w1.w;
    }
  }
  #pragma unroll
  for (int off = 32; off; off >>= 1) {
    #pragma unroll
    for (int e = 0; e < 8; ++e) acc[e] += __shfl_down(acc[e], off);
  }
  if (lane == 0) {
    #pragma unroll
    for (int e = 0; e < 8; ++e) {
      float v = acc[e] > 0.f ? acc[e] : 0.f;
      w[n * 8 + e] = v;
      rout[n * 8 + e] = v;
    }
  }
}

// ---- GEMM1: fused gate+up, 128x64 tile, epilogue silu(g)*u*w -> A2 (bf16) ----
// xb [N][H] bf16, Wg/Wu [E][F][H] bf16 (B^T layout). 1-D grid, XCD-chunk swizzled.
// Per XCD: contiguous logical range (expert-major, then xq, y fastest -> B panel L2-resident).
__global__ void __launch_bounds__(256, 4) k_gemm1(
    const unsigned short* __restrict__ xb,
    const unsigned short* __restrict__ Wg,
    const unsigned short* __restrict__ Wu,
    const float* __restrict__ w,
    unsigned short* __restrict__ A2,
    int e0, int k2g, int nwg) {
  __shared__ char lds[16384];
  char* As = lds;           // 128 rows x 64B
  char* Bg = lds + 8192;    //  64 rows x 64B
  char* Bu = lds + 12288;   //  64 rows x 64B
  const int tid = threadIdx.x;
  const int lane = tid & 63, wv = tid >> 6;

  // XCD-chunk bijective swizzle (nwg divisible by 8)
  const int h = blockIdx.x;
  const int chunk = nwg >> 3;
  const int L = (h & 7) * chunk + (h >> 3);
  const int eloc = L >> 10;            // expert within pass (1024 blocks/expert)
  const int xq   = (L >> 6) & 15;      // f-block (64 cols)
  const int y    = L & 63;             // m-block (128 rows), fastest
  const int e = e0 + eloc;
  const int bm = y * 128;
  const int bf = xq * 64;
  const int wr = wv >> 1, wc = wv & 1;

  const unsigned short* gA  = xb + (size_t)bm * HD;
  const unsigned short* gBg = Wg + ((size_t)e * FF + bf) * HD;
  const unsigned short* gBu = Wu + ((size_t)e * FF + bf) * HD;

  f32x4 zero = {0.f, 0.f, 0.f, 0.f};
  f32x4 accg[4][2], accu[4][2];
  #pragma unroll
  for (int i = 0; i < 4; ++i) {
    #pragma unroll
    for (int j = 0; j < 2; ++j) { accg[i][j] = zero; accu[i][j] = zero; }
  }

  const int srow = tid >> 2;           // staging row (0..63)
  const int sch  = (tid & 3) * 8;      // staging k-chunk (elements)
  const int fr   = lane & 15;          // fragment row/col
  const int kb   = (lane >> 4) * 16;   // fragment k-group byte offset

  for (int k0 = 0; k0 < HD; k0 += 32) {
    // A: 128 rows -> 2 loads/thread; Bg/Bu: 64 rows -> 1 load/thread each
    gl_lds16(gA  + (size_t)srow * HD + k0 + sch,        As + (size_t)tid * 16);
    gl_lds16(gA  + (size_t)(srow + 64) * HD + k0 + sch, As + 4096 + (size_t)tid * 16);
    gl_lds16(gBg + (size_t)srow * HD + k0 + sch,        Bg + (size_t)tid * 16);
    gl_lds16(gBu + (size_t)srow * HD + k0 + sch,        Bu + (size_t)tid * 16);
    __syncthreads();
    bf16x8 a[4];
    #pragma unroll
    for (int i = 0; i < 4; ++i)
      a[i] = *(const bf16x8*)(As + (wr * 64 + i * 16 + fr) * 64 + kb);
    #pragma unroll
    for (int j = 0; j < 2; ++j) {
      bf16x8 bg = *(const bf16x8*)(Bg + (wc * 32 + j * 16 + fr) * 64 + kb);
      bf16x8 bu = *(const bf16x8*)(Bu + (wc * 32 + j * 16 + fr) * 64 + kb);
      #pragma unroll
      for (int i = 0; i < 4; ++i) {
        accg[i][j] = __builtin_amdgcn_mfma_f32_16x16x32_bf16(a[i], bg, accg[i][j], 0, 0, 0);
        accu[i][j] = __builtin_amdgcn_mfma_f32_16x16x32_bf16(a[i], bu, accu[i][j], 0, 0, 0);
      }
    }
    __syncthreads();
  }

  const int lrow = (lane >> 4) * 4;
  const int lcol = lane & 15;
  #pragma unroll
  for (int i = 0; i < 4; ++i) {
    #pragma unroll
    for (int r = 0; r < 4; ++r) {
      int n = bm + wr * 64 + i * 16 + lrow + r;
      float wn = w[n * 8 + e];
      size_t obase = (size_t)n * k2g + (size_t)eloc * FF + bf + wc * 32 + lcol;
      #pragma unroll
      for (int j = 0; j < 2; ++j) {
        float g = accg[i][j][r];
        float u = accu[i][j][r];
        float s = g / (1.f + __expf(-g));
        A2[obase + j * 16] = f2bf(s * u * wn);
      }
    }
  }
}

// ---- GEMM2: out(+)= A2 @ Wd. A2 [N][k2g] bf16, Wd [H][NE*FF] bf16 (pre-offset). ----
// 1-D grid 1024, XCD-chunk swizzled, x fastest -> A2 row-panel (2MB) L2-resident.
__global__ void __launch_bounds__(256) k_gemm2(
    const unsigned short* __restrict__ A2,
    const unsigned short* __restrict__ Wd,
    float* __restrict__ out,
    int k2g, int accum) {
  __shared__ char lds[16384];
  char* As = lds;
  char* Bs = lds + 8192;
  const int tid = threadIdx.x;
  const int lane = tid & 63, wv = tid >> 6;

  const int h = blockIdx.x;
  const int L = (h & 7) * 128 + (h >> 3);
  const int y = L >> 4;       // m-block
  const int x = L & 15;       // n-block, fastest
  const int bm = y * 128;
  const int bn = x * 128;
  const int wr = wv >> 1, wc = wv & 1;

  const unsigned short* gA = A2 + (size_t)bm * k2g;
  const unsigned short* gB = Wd + (size_t)bn * (NE * FF);

  f32x4 zero = {0.f, 0.f, 0.f, 0.f};
  f32x4 acc[4][4];
  #pragma unroll
  for (int i = 0; i < 4; ++i) {
    #pragma unroll
    for (int j = 0; j < 4; ++j) acc[i][j] = zero;
  }

  const int srow = lane >> 2;
  const int sch  = (lane & 3) * 8;
  const int fr   = lane & 15;
  const int kb   = (lane >> 4) * 16;

  for (int k0 = 0; k0 < k2g; k0 += 32) {
    #pragma unroll
    for (int r = 0; r < 2; ++r) {
      int row = r * 64 + wv * 16 + srow;
      gl_lds16(gA + (size_t)row * k2g + k0 + sch,        As + (size_t)(r * 4096 + wv * 1024));
      gl_lds16(gB + (size_t)row * (NE * FF) + k0 + sch,  Bs + (size_t)(r * 4096 + wv * 1024));
    }
    __syncthreads();
    bf16x8 a[4];
    #pragma unroll
    for (int i = 0; i < 4; ++i)
      a[i] = *(const bf16x8*)(As + (wr * 64 + i * 16 + fr) * 64 + kb);
    #pragma unroll
    for (int j = 0; j < 4; ++j) {
      bf16x8 b = *(const bf16x8*)(Bs + (wc * 64 + j * 16 + fr) * 64 + kb);
      #pragma unroll
      for (int i = 0; i < 4; ++i)
        acc[i][j] = __builtin_amdgcn_mfma_f32_16x16x32_bf16(a[i], b, acc[i][j], 0, 0, 0);
    }
    __syncthreads();
  }

  const int lrow = (lane >> 4) * 4;
  const int lcol = lane & 15;
  #pragma unroll
  for (int i = 0; i < 4; ++i) {
    #pragma unroll
    for (int r = 0; r < 4; ++r) {
      int n = bm + wr * 64 + i * 16 + lrow + r;
      float* op = out + (size_t)n * HD + bn + wc * 64 + lcol;
      #pragma unroll
      for (int j = 0; j < 4; ++j) {
        float v = acc[i][j][r];
        op[j * 16] = accum ? (op[j * 16] + v) : v;
      }
    }
  }
}

extern "C" void kernel_launch(void* const* d_in, const int* in_sizes, int n_in,
                              void* d_out, int out_size, void* d_ws, size_t ws_size,
                              hipStream_t stream) {
  (void)in_sizes; (void)out_size;
  if (n_in < 5) return;
  const float* x  = (const float*)d_in[0];
  const float* Wr = (const float*)d_in[1];
  const float* Wg = (const float*)d_in[2];
  const float* Wu = (const float*)d_in[3];
  const float* Wd = (const float*)d_in[4];
  float* out  = (float*)d_out;
  float* rout = out + (size_t)N_TOK * HD;

  char* ws = (char*)d_ws;
  const size_t SZ_XB = (size_t)N_TOK * HD * 2;      // 33,554,432 B
  const size_t SZ_W  = (size_t)NE * HD * FF * 2;    // 33,554,432 B each
  unsigned short* xb    = (unsigned short*)(ws);
  unsigned short* Wg_bt = (unsigned short*)(ws + SZ_XB);
  unsigned short* Wu_bt = (unsigned short*)(ws + SZ_XB + SZ_W);
  unsigned short* Wd_bt = (unsigned short*)(ws + SZ_XB + 2 * SZ_W);
  float*          wbuf  = (float*)(ws + SZ_XB + 3 * SZ_W);
  const size_t fixed = SZ_XB + 3 * SZ_W + (size_t)N_TOK * NE * 4;  // 134,479,872 B
  unsigned short* A2    = (unsigned short*)(ws + fixed);

  const size_t perE = (size_t)N_TOK * FF * 2;       // 16,777,216 B per expert slab
  int G = 8;
  while (G > 1 && fixed + (size_t)G * perE > ws_size) G >>= 1;

  // conversions
  k_conv<<<4096, 256, 0, stream>>>(x, xb, (N_TOK * HD) / 4);
  dim3 tb(32, 8);
  k_tconv<<<dim3(FF / 32, HD / 32, NE), tb, 0, stream>>>(
      Wg, Wg_bt, HD, FF, (size_t)HD * FF, (size_t)FF * HD, (size_t)HD);
  k_tconv<<<dim3(FF / 32, HD / 32, NE), tb, 0, stream>>>(
      Wu, Wu_bt, HD, FF, (size_t)HD * FF, (size_t)FF * HD, (size_t)HD);
  k_tconv<<<dim3(HD / 32, FF / 32, NE), tb, 0, stream>>>(
      Wd, Wd_bt, FF, HD, (size_t)FF * HD, (size_t)FF, (size_t)(NE * FF));

  // router (fp32 exact) -> wbuf + d_out router section
  k_router<<<N_TOK / 4, 256, 0, stream>>>(x, Wr, wbuf, rout);

  // expert GEMMs (G experts per pass; accumulate across passes)
  const int k2g = G * FF;
  for (int e0 = 0; e0 < NE; e0 += G) {
    const int nwg1 = (FF / 64) * (N_TOK / 128) * G;  // 1024*G, %8==0
    k_gemm1<<<nwg1, 256, 0, stream>>>(xb, Wg_bt, Wu_bt, wbuf, A2, e0, k2g, nwg1);
    k_gemm2<<<(HD / 128) * (N_TOK / 128), 256, 0, stream>>>(
        A2, Wd_bt + (size_t)e0 * FF, out, k2g, e0 != 0);
  }
}

// Round 3
// 951.734 us; speedup vs baseline: 1.9644x; 1.3527x over previous
//
#include <hip/hip_runtime.h>
#include <hip/hip_bf16.h>

#define N_TOK 8192
#define HD    2048
#define NE    8
#define FF    1024

using f32x4  = __attribute__((ext_vector_type(4))) float;
using bf16x8 = __attribute__((ext_vector_type(8))) __bf16;

__device__ __forceinline__ unsigned short f2bf(float f) {
  unsigned u = __float_as_uint(f);
  u += 0x7FFFu + ((u >> 16) & 1u);   // RTNE (inputs are finite/normal)
  return (unsigned short)(u >> 16);
}

__device__ __forceinline__ void gl_lds16(const void* g, void* l) {
  __builtin_amdgcn_global_load_lds((__attribute__((address_space(1))) void*)g,
                                   (__attribute__((address_space(3))) void*)l,
                                   16, 0, 0);
}

// Stage a 256-row x 64-col bf16 tile (32KB): 4 calls/thread, pre-swizzled global src.
__device__ __forceinline__ void stage256(const unsigned short* g, size_t lda, int k0,
                                         char* slotbase, int wv, int sr8, int scol) {
  #pragma unroll
  for (int c = 0; c < 4; ++c) {
    const int grp = c * 8 + wv;
    gl_lds16(g + (size_t)(grp * 8 + sr8) * lda + k0 + scol, slotbase + grp * 1024);
  }
}
// 128-row tile (16KB): 2 calls/thread.
__device__ __forceinline__ void stage128(const unsigned short* g, size_t lda, int k0,
                                         char* slotbase, int wv, int sr8, int scol) {
  #pragma unroll
  for (int c = 0; c < 2; ++c) {
    const int grp = c * 8 + wv;
    gl_lds16(g + (size_t)(grp * 8 + sr8) * lda + k0 + scol, slotbase + grp * 1024);
  }
}
// 64-row tile (8KB): 1 call/thread.
__device__ __forceinline__ void stage64(const unsigned short* g, size_t lda, int k0,
                                        char* slotbase, int wv, int sr8, int scol) {
  gl_lds16(g + (size_t)(wv * 8 + sr8) * lda + k0 + scol, slotbase + wv * 1024);
}

// ---- elementwise fp32 -> bf16 convert (vectorized) ----
__global__ void k_conv(const float* __restrict__ in, unsigned short* __restrict__ out, int n4) {
  int stride = gridDim.x * blockDim.x;
  for (int i = blockIdx.x * blockDim.x + threadIdx.x; i < n4; i += stride) {
    float4 v = reinterpret_cast<const float4*>(in)[i];
    ushort4 o;
    o.x = f2bf(v.x); o.y = f2bf(v.y); o.z = f2bf(v.z); o.w = f2bf(v.w);
    reinterpret_cast<ushort4*>(out)[i] = o;
  }
}

// ---- tiled transpose + convert: in[z][R][C] fp32 -> out[z*out_z + c*ostride + r] bf16 ----
__global__ void k_tconv(const float* __restrict__ in, unsigned short* __restrict__ out,
                        int R, int C, size_t in_z, size_t out_z, size_t ostride) {
  __shared__ float tile[32][33];
  const int z = blockIdx.z;
  const int c0 = blockIdx.x * 32, r0 = blockIdx.y * 32;
  const int tx = threadIdx.x, ty = threadIdx.y;
  const float* ip = in + (size_t)z * in_z;
  unsigned short* op = out + (size_t)z * out_z;
  #pragma unroll
  for (int i = ty; i < 32; i += 8)
    tile[i][tx] = ip[(size_t)(r0 + i) * C + (c0 + tx)];
  __syncthreads();
  #pragma unroll
  for (int i = ty; i < 32; i += 8)
    op[(size_t)(c0 + i) * ostride + (r0 + tx)] = f2bf(tile[tx][i]);
}

// ---- router: w = relu(x @ W_router), fp32 exact. one wave per token ----
__global__ void k_router(const float* __restrict__ x, const float* __restrict__ Wr,
                         float* __restrict__ w, float* __restrict__ rout) {
  const int lane = threadIdx.x & 63, wv = threadIdx.x >> 6;
  const int n = blockIdx.x * 4 + wv;
  const float* xr = x + (size_t)n * HD + lane * 32;
  const float* wbase = Wr + (size_t)lane * 32 * NE;
  float acc[8];
  #pragma unroll
  for (int e = 0; e < 8; ++e) acc[e] = 0.f;
  #pragma unroll
  for (int kk = 0; kk < 32; kk += 4) {
    float4 xv = *reinterpret_cast<const float4*>(xr + kk);
    #pragma unroll
    for (int t = 0; t < 4; ++t) {
      const float* wrow = wbase + (kk + t) * 8;
      float4 w0 = *reinterpret_cast<const float4*>(wrow);
      float4 w1 = *reinterpret_cast<const float4*>(wrow + 4);
      float xs = (t == 0) ? xv.x : (t == 1) ? xv.y : (t == 2) ? xv.z : xv.w;
      acc[0] += xs * w0.x; acc[1] += xs * w0.y; acc[2] += xs * w0.z; acc[3] += xs * w0.w;
      acc[4] += xs * w1.x; acc[5] += xs * w1.y; acc[6] += xs * w1.z; acc[7] += xs * w1.w;
    }
  }
  #pragma unroll
  for (int off = 32; off; off >>= 1) {
    #pragma unroll
    for (int e = 0; e < 8; ++e) acc[e] += __shfl_down(acc[e], off);
  }
  if (lane == 0) {
    #pragma unroll
    for (int e = 0; e < 8; ++e) {
      float v = acc[e] > 0.f ? acc[e] : 0.f;
      w[n * 8 + e] = v;
      rout[n * 8 + e] = v;
    }
  }
}

// =======================================================================
// GEMM1: fused gate+up, 256x64 tile, BK=64, pipelined (A 3-slot, B 2-slot),
// T2 swizzle, counted vmcnt(4). Epilogue silu(g)*u*w -> A2 (bf16).
// =======================================================================
#define G1_PHASE(mq) do {                                                        \
    const char* Ab_ = As + sA * 32768 + (wr * 128 + (mq) * 64) * 128 + rb;       \
    const char* Bg_ = Bgs + sBr * 8192 + (wc * 16) * 128 + rb;                   \
    const char* Bu_ = Bus + sBr * 8192 + (wc * 16) * 128 + rb;                   \
    bf16x8 av_[4][2];                                                            \
    _Pragma("unroll")                                                            \
    for (int i = 0; i < 4; ++i) {                                                \
      av_[i][0] = *(const bf16x8*)(Ab_ + i * 2048 + cp0);                        \
      av_[i][1] = *(const bf16x8*)(Ab_ + i * 2048 + cp1);                        \
    }                                                                            \
    bf16x8 bg0_ = *(const bf16x8*)(Bg_ + cp0);                                   \
    bf16x8 bg1_ = *(const bf16x8*)(Bg_ + cp1);                                   \
    bf16x8 bu0_ = *(const bf16x8*)(Bu_ + cp0);                                   \
    bf16x8 bu1_ = *(const bf16x8*)(Bu_ + cp1);                                   \
    __builtin_amdgcn_s_setprio(1);                                               \
    _Pragma("unroll")                                                            \
    for (int i = 0; i < 4; ++i) {                                                \
      ag[(mq)*4+i] = __builtin_amdgcn_mfma_f32_16x16x32_bf16(av_[i][0], bg0_, ag[(mq)*4+i], 0,0,0); \
      au[(mq)*4+i] = __builtin_amdgcn_mfma_f32_16x16x32_bf16(av_[i][0], bu0_, au[(mq)*4+i], 0,0,0); \
      ag[(mq)*4+i] = __builtin_amdgcn_mfma_f32_16x16x32_bf16(av_[i][1], bg1_, ag[(mq)*4+i], 0,0,0); \
      au[(mq)*4+i] = __builtin_amdgcn_mfma_f32_16x16x32_bf16(av_[i][1], bu1_, au[(mq)*4+i], 0,0,0); \
    }                                                                            \
    __builtin_amdgcn_s_setprio(0);                                               \
  } while (0)

__global__ void __launch_bounds__(512, 2) k_gemm1(
    const unsigned short* __restrict__ xb,
    const unsigned short* __restrict__ Wg,
    const unsigned short* __restrict__ Wu,
    const float* __restrict__ w,
    unsigned short* __restrict__ A2,
    int e0, int k2g, int nwg) {
  extern __shared__ char lds[];
  char* As  = lds;                  // 3 x 32768 = 98304
  char* Bgs = lds + 98304;          // 2 x 8192
  char* Bus = lds + 114688;         // 2 x 8192  (total 131072)
  const int tid = threadIdx.x;
  const int l = tid & 63, wv = tid >> 6;

  // XCD-chunk bijective swizzle; expert-major, 4f x 8y sub-chunks (B L2-resident)
  const int h = blockIdx.x;
  const int chunk = nwg >> 3;
  const int L = (h & 7) * chunk + (h >> 3);
  const int eloc = L >> 9;                 // 512 blocks/expert
  const int e = e0 + eloc;
  const int idx = L & 511;                 // 16 f-blocks x 32 y-blocks
  const int sub = idx >> 5;                // 16 sub-chunks of 4f x 8y
  const int f = ((sub & 3) << 2) | ((idx >> 3) & 3);
  const int y = ((sub >> 2) << 3) | (idx & 7);
  const int bm = y << 8;                   // 256-row tile
  const int bf = f << 6;                   // 64-col f tile
  const int wr = wv >> 2, wc = wv & 3;     // 2M x 4N waves

  const unsigned short* gA  = xb + (size_t)bm * HD;
  const unsigned short* gBg = Wg + ((size_t)e * FF + bf) * HD;
  const unsigned short* gBu = Wu + ((size_t)e * FF + bf) * HD;

  // staging: pre-swizzled global source, linear LDS dest (rule #21)
  const int sr8  = l >> 3;
  const int scol = ((l & 7) ^ sr8) << 3;   // elements
  // frag reads: same involution on the read side
  const int fr  = l & 15;
  const int rb  = fr << 7;                 // row byte (128B rows)
  const int kc  = (l >> 4) << 4;
  const int swz = (l & 7) << 4;
  const int cp0 = kc ^ swz;
  const int cp1 = (64 + kc) ^ swz;

  f32x4 ag[8], au[8];
  const f32x4 zero = {0.f, 0.f, 0.f, 0.f};
  #pragma unroll
  for (int i = 0; i < 8; ++i) { ag[i] = zero; au[i] = zero; }

  // prologue: A(0), B(0), A(1); wait oldest 6, leave A(1) in flight
  stage256(gA, HD, 0, As, wv, sr8, scol);
  stage64(gBg, HD, 0, Bgs, wv, sr8, scol);
  stage64(gBu, HD, 0, Bus, wv, sr8, scol);
  stage256(gA, HD, 64, As + 32768, wv, sr8, scol);
  asm volatile("s_waitcnt vmcnt(4)" ::: "memory");
  __builtin_amdgcn_s_barrier();
  __builtin_amdgcn_sched_barrier(0);

  const int NT = HD / 64;   // 32
  int sA = 0;               // A read slot (t % 3)
  for (int t = 0; t < NT; ++t) {
    const int tB = (t + 1 < NT) ? t + 1 : NT - 1;
    const int tA = (t + 2 < NT) ? t + 2 : NT - 1;
    const int sBw = (t + 1) & 1;
    const int sBr = t & 1;
    const int sAw = (sA >= 1) ? sA - 1 : 2;   // (sA+2)%3
    stage64(gBg, HD, tB * 64, Bgs + sBw * 8192, wv, sr8, scol);
    stage64(gBu, HD, tB * 64, Bus + sBw * 8192, wv, sr8, scol);
    G1_PHASE(0);
    stage256(gA, HD, tA * 64, As + sAw * 32768, wv, sr8, scol);
    G1_PHASE(1);
    asm volatile("s_waitcnt vmcnt(4)" ::: "memory");  // keep A(t+2) in flight
    __builtin_amdgcn_s_barrier();
    __builtin_amdgcn_sched_barrier(0);
    sA = (sA == 2) ? 0 : sA + 1;
  }

  // epilogue: silu(g)*u*w -> A2 bf16
  const int orow = (l >> 4) << 2;
  #pragma unroll
  for (int am = 0; am < 8; ++am) {
    #pragma unroll
    for (int rr = 0; rr < 4; ++rr) {
      const int n = bm + wr * 128 + am * 16 + orow + rr;
      const float wn = w[n * 8 + e];
      const float g = ag[am][rr];
      const float u = au[am][rr];
      const float s = g / (1.f + __expf(-g));
      A2[(size_t)n * k2g + (size_t)eloc * FF + bf + wc * 16 + fr] = f2bf(s * u * wn);
    }
  }
}

// =======================================================================
// GEMM2: out(+)= A2 @ Wd, 256x128 tile, BK=64, same pipeline structure.
// =======================================================================
#define G2_PHASE(mq) do {                                                        \
    const char* Ab_ = As + sA * 32768 + (wr * 128 + (mq) * 64) * 128 + rb;       \
    const char* Bb_ = Bs + sBr * 16384 + (wc * 32) * 128 + rb;                   \
    bf16x8 av_[4][2];                                                            \
    bf16x8 bv_[2][2];                                                            \
    _Pragma("unroll")                                                            \
    for (int i = 0; i < 4; ++i) {                                                \
      av_[i][0] = *(const bf16x8*)(Ab_ + i * 2048 + cp0);                        \
      av_[i][1] = *(const bf16x8*)(Ab_ + i * 2048 + cp1);                        \
    }                                                                            \
    _Pragma("unroll")                                                            \
    for (int j = 0; j < 2; ++j) {                                                \
      bv_[j][0] = *(const bf16x8*)(Bb_ + j * 2048 + cp0);                        \
      bv_[j][1] = *(const bf16x8*)(Bb_ + j * 2048 + cp1);                        \
    }                                                                            \
    __builtin_amdgcn_s_setprio(1);                                               \
    _Pragma("unroll")                                                            \
    for (int i = 0; i < 4; ++i) {                                                \
      _Pragma("unroll")                                                          \
      for (int j = 0; j < 2; ++j) {                                              \
        acc[(mq)*4+i][j] = __builtin_amdgcn_mfma_f32_16x16x32_bf16(av_[i][0], bv_[j][0], acc[(mq)*4+i][j], 0,0,0); \
        acc[(mq)*4+i][j] = __builtin_amdgcn_mfma_f32_16x16x32_bf16(av_[i][1], bv_[j][1], acc[(mq)*4+i][j], 0,0,0); \
      }                                                                          \
    }                                                                            \
    __builtin_amdgcn_s_setprio(0);                                               \
  } while (0)

__global__ void __launch_bounds__(512, 2) k_gemm2(
    const unsigned short* __restrict__ A2,
    const unsigned short* __restrict__ Wd,
    float* __restrict__ out,
    int k2g, int accum) {
  extern __shared__ char lds[];
  char* As = lds;                   // 3 x 32768 = 98304
  char* Bs = lds + 98304;           // 2 x 16384 (total 131072)
  const int tid = threadIdx.x;
  const int l = tid & 63, wv = tid >> 6;

  // XCD-chunk swizzle: per XCD 4y x 16x (x fastest): A2 panels fetched once/XCD
  const int h = blockIdx.x;
  const int L = (h & 7) * 64 + (h >> 3);   // grid 512
  const int y = L >> 4;                    // 32 m-blocks
  const int x = L & 15;                    // 16 n-blocks
  const int bm = y << 8;
  const int bn = x << 7;
  const int wr = wv >> 2, wc = wv & 3;

  const unsigned short* gA = A2 + (size_t)bm * k2g;
  const unsigned short* gB = Wd + (size_t)bn * (NE * FF);

  const int sr8  = l >> 3;
  const int scol = ((l & 7) ^ sr8) << 3;
  const int fr  = l & 15;
  const int rb  = fr << 7;
  const int kc  = (l >> 4) << 4;
  const int swz = (l & 7) << 4;
  const int cp0 = kc ^ swz;
  const int cp1 = (64 + kc) ^ swz;

  f32x4 acc[8][2];
  const f32x4 zero = {0.f, 0.f, 0.f, 0.f};
  #pragma unroll
  for (int i = 0; i < 8; ++i) { acc[i][0] = zero; acc[i][1] = zero; }

  stage256(gA, k2g, 0, As, wv, sr8, scol);
  stage128(gB, NE * FF, 0, Bs, wv, sr8, scol);
  stage256(gA, k2g, 64, As + 32768, wv, sr8, scol);
  asm volatile("s_waitcnt vmcnt(4)" ::: "memory");
  __builtin_amdgcn_s_barrier();
  __builtin_amdgcn_sched_barrier(0);

  const int NT = k2g / 64;
  int sA = 0;
  for (int t = 0; t < NT; ++t) {
    const int tB = (t + 1 < NT) ? t + 1 : NT - 1;
    const int tA = (t + 2 < NT) ? t + 2 : NT - 1;
    const int sBw = (t + 1) & 1;
    const int sBr = t & 1;
    const int sAw = (sA >= 1) ? sA - 1 : 2;
    stage128(gB, NE * FF, tB * 64, Bs + sBw * 16384, wv, sr8, scol);
    G2_PHASE(0);
    stage256(gA, k2g, tA * 64, As + sAw * 32768, wv, sr8, scol);
    G2_PHASE(1);
    asm volatile("s_waitcnt vmcnt(4)" ::: "memory");
    __builtin_amdgcn_s_barrier();
    __builtin_amdgcn_sched_barrier(0);
    sA = (sA == 2) ? 0 : sA + 1;
  }

  const int orow = (l >> 4) << 2;
  #pragma unroll
  for (int am = 0; am < 8; ++am) {
    #pragma unroll
    for (int rr = 0; rr < 4; ++rr) {
      const int n = bm + wr * 128 + am * 16 + orow + rr;
      float* op = out + (size_t)n * HD + bn + wc * 32 + fr;
      #pragma unroll
      for (int j = 0; j < 2; ++j) {
        const float v = acc[am][j][rr];
        op[j * 16] = accum ? (op[j * 16] + v) : v;
      }
    }
  }
}

extern "C" void kernel_launch(void* const* d_in, const int* in_sizes, int n_in,
                              void* d_out, int out_size, void* d_ws, size_t ws_size,
                              hipStream_t stream) {
  (void)in_sizes; (void)out_size;
  if (n_in < 5) return;
  const float* x  = (const float*)d_in[0];
  const float* Wr = (const float*)d_in[1];
  const float* Wg = (const float*)d_in[2];
  const float* Wu = (const float*)d_in[3];
  const float* Wd = (const float*)d_in[4];
  float* out  = (float*)d_out;
  float* rout = out + (size_t)N_TOK * HD;

  hipFuncSetAttribute((const void*)k_gemm1, hipFuncAttributeMaxDynamicSharedMemorySize, 131072);
  hipFuncSetAttribute((const void*)k_gemm2, hipFuncAttributeMaxDynamicSharedMemorySize, 131072);

  char* ws = (char*)d_ws;
  const size_t SZ_XB = (size_t)N_TOK * HD * 2;      // 33,554,432 B
  const size_t SZ_W  = (size_t)NE * HD * FF * 2;    // 33,554,432 B each
  unsigned short* xb    = (unsigned short*)(ws);
  unsigned short* Wg_bt = (unsigned short*)(ws + SZ_XB);
  unsigned short* Wu_bt = (unsigned short*)(ws + SZ_XB + SZ_W);
  unsigned short* Wd_bt = (unsigned short*)(ws + SZ_XB + 2 * SZ_W);
  float*          wbuf  = (float*)(ws + SZ_XB + 3 * SZ_W);
  const size_t fixed = SZ_XB + 3 * SZ_W + (size_t)N_TOK * NE * 4;  // 134,479,872 B
  unsigned short* A2    = (unsigned short*)(ws + fixed);

  const size_t perE = (size_t)N_TOK * FF * 2;       // 16,777,216 B per expert slab
  int G = 8;
  while (G > 1 && fixed + (size_t)G * perE > ws_size) G >>= 1;

  // conversions
  k_conv<<<4096, 256, 0, stream>>>(x, xb, (N_TOK * HD) / 4);
  dim3 tb(32, 8);
  k_tconv<<<dim3(FF / 32, HD / 32, NE), tb, 0, stream>>>(
      Wg, Wg_bt, HD, FF, (size_t)HD * FF, (size_t)FF * HD, (size_t)HD);
  k_tconv<<<dim3(FF / 32, HD / 32, NE), tb, 0, stream>>>(
      Wu, Wu_bt, HD, FF, (size_t)HD * FF, (size_t)FF * HD, (size_t)HD);
  k_tconv<<<dim3(HD / 32, FF / 32, NE), tb, 0, stream>>>(
      Wd, Wd_bt, FF, HD, (size_t)FF * HD, (size_t)FF, (size_t)(NE * FF));

  // router (fp32 exact) -> wbuf + d_out router section
  k_router<<<N_TOK / 4, 256, 0, stream>>>(x, Wr, wbuf, rout);

  // expert GEMMs (G experts per pass; accumulate across passes)
  const int k2g = G * FF;
  for (int e0 = 0; e0 < NE; e0 += G) {
    const int nwg1 = 512 * G;   // 16f x 32y per expert
    k_gemm1<<<nwg1, 512, 131072, stream>>>(xb, Wg_bt, Wu_bt, wbuf, A2, e0, k2g, nwg1);
    k_gemm2<<<512, 512, 131072, stream>>>(A2, Wd_bt + (size_t)e0 * FF, out, k2g, e0 != 0);
  }
}

// Round 4
// 769.849 us; speedup vs baseline: 2.4286x; 1.2363x over previous
//
#include <hip/hip_runtime.h>
#include <hip/hip_bf16.h>

#define N_TOK 8192
#define HD    2048
#define NE    8
#define FF    1024

using f32x4  = __attribute__((ext_vector_type(4))) float;
using bf16x8 = __attribute__((ext_vector_type(8))) __bf16;

__device__ __forceinline__ unsigned short f2bf(float f) {
  unsigned u = __float_as_uint(f);
  u += 0x7FFFu + ((u >> 16) & 1u);   // RTNE (inputs are finite/normal)
  return (unsigned short)(u >> 16);
}

__device__ __forceinline__ void gl_lds16(const void* g, void* l) {
  __builtin_amdgcn_global_load_lds((__attribute__((address_space(1))) void*)g,
                                   (__attribute__((address_space(3))) void*)l,
                                   16, 0, 0);
}

// Stage a 256-row x 64-col bf16 tile (32KB): 4 calls/thread, pre-swizzled global src.
__device__ __forceinline__ void stage256(const unsigned short* g, size_t lda, int k0,
                                         char* slotbase, int wv, int sr8, int scol) {
  #pragma unroll
  for (int c = 0; c < 4; ++c) {
    const int grp = c * 8 + wv;
    gl_lds16(g + (size_t)(grp * 8 + sr8) * lda + k0 + scol, slotbase + grp * 1024);
  }
}
// indexed variant: per-thread row base pointers (compacted token gather)
__device__ __forceinline__ void stage256i(const unsigned short* const aP[4], int k0,
                                          char* slotbase, int wv) {
  #pragma unroll
  for (int c = 0; c < 4; ++c) {
    const int grp = c * 8 + wv;
    gl_lds16(aP[c] + k0, slotbase + grp * 1024);
  }
}
// 128-row tile (16KB): 2 calls/thread.
__device__ __forceinline__ void stage128(const unsigned short* g, size_t lda, int k0,
                                         char* slotbase, int wv, int sr8, int scol) {
  #pragma unroll
  for (int c = 0; c < 2; ++c) {
    const int grp = c * 8 + wv;
    gl_lds16(g + (size_t)(grp * 8 + sr8) * lda + k0 + scol, slotbase + grp * 1024);
  }
}
// 64-row tile (8KB): 1 call/thread.
__device__ __forceinline__ void stage64(const unsigned short* g, size_t lda, int k0,
                                        char* slotbase, int wv, int sr8, int scol) {
  gl_lds16(g + (size_t)(wv * 8 + sr8) * lda + k0 + scol, slotbase + wv * 1024);
}

// ---- tiled transpose + convert: in[z][R][C] fp32 -> out[z*out_z + c*ostride + r] bf16 ----
__global__ void k_tconv(const float* __restrict__ in, unsigned short* __restrict__ out,
                        int R, int C, size_t in_z, size_t out_z, size_t ostride) {
  __shared__ float tile[32][33];
  const int z = blockIdx.z;
  const int c0 = blockIdx.x * 32, r0 = blockIdx.y * 32;
  const int tx = threadIdx.x, ty = threadIdx.y;
  const float* ip = in + (size_t)z * in_z;
  unsigned short* op = out + (size_t)z * out_z;
  #pragma unroll
  for (int i = ty; i < 32; i += 8)
    tile[i][tx] = ip[(size_t)(r0 + i) * C + (c0 + tx)];
  __syncthreads();
  #pragma unroll
  for (int i = ty; i < 32; i += 8)
    op[(size_t)(c0 + i) * ostride + (r0 + tx)] = f2bf(tile[tx][i]);
}

// ---- router: w = relu(x @ W_router), fp32 exact; also emits x in bf16. ----
__global__ void k_router(const float* __restrict__ x, const float* __restrict__ Wr,
                         float* __restrict__ w, float* __restrict__ rout,
                         unsigned short* __restrict__ xb) {
  const int lane = threadIdx.x & 63, wv = threadIdx.x >> 6;
  const int n = blockIdx.x * 4 + wv;
  const float* xr = x + (size_t)n * HD + lane * 32;
  unsigned short* xbr = xb + (size_t)n * HD + lane * 32;
  const float* wbase = Wr + (size_t)lane * 32 * NE;
  float acc[8];
  #pragma unroll
  for (int e = 0; e < 8; ++e) acc[e] = 0.f;
  #pragma unroll
  for (int kk = 0; kk < 32; kk += 4) {
    float4 xv = *reinterpret_cast<const float4*>(xr + kk);
    ushort4 o;
    o.x = f2bf(xv.x); o.y = f2bf(xv.y); o.z = f2bf(xv.z); o.w = f2bf(xv.w);
    *reinterpret_cast<ushort4*>(xbr + kk) = o;
    #pragma unroll
    for (int t = 0; t < 4; ++t) {
      const float* wrow = wbase + (kk + t) * 8;
      float4 w0 = *reinterpret_cast<const float4*>(wrow);
      float4 w1 = *reinterpret_cast<const float4*>(wrow + 4);
      float xs = (t == 0) ? xv.x : (t == 1) ? xv.y : (t == 2) ? xv.z : xv.w;
      acc[0] += xs * w0.x; acc[1] += xs * w0.y; acc[2] += xs * w0.z; acc[3] += xs * w0.w;
      acc[4] += xs * w1.x; acc[5] += xs * w1.y; acc[6] += xs * w1.z; acc[7] += xs * w1.w;
    }
  }
  #pragma unroll
  for (int off = 32; off; off >>= 1) {
    #pragma unroll
    for (int e = 0; e < 8; ++e) acc[e] += __shfl_down(acc[e], off);
  }
  if (lane == 0) {
    #pragma unroll
    for (int e = 0; e < 8; ++e) {
      float v = acc[e] > 0.f ? acc[e] : 0.f;
      w[n * 8 + e] = v;
      rout[n * 8 + e] = v;
    }
  }
}

// ---- per-expert stable compaction: idx[e][0..Me) = tokens with w>0, pad to 256-mult ----
__global__ void k_compact(const float* __restrict__ w, int* __restrict__ idx,
                          int* __restrict__ cnt) {
  const int e = blockIdx.x;
  __shared__ int base;
  __shared__ int scan[4];
  if (threadIdx.x == 0) base = 0;
  __syncthreads();
  const int lane = threadIdx.x & 63, wvi = threadIdx.x >> 6;
  for (int c0 = 0; c0 < N_TOK; c0 += 256) {
    const int n = c0 + threadIdx.x;
    const bool act = w[n * 8 + e] > 0.f;
    unsigned long long m = __ballot(act);
    const int pre  = __popcll(m & ((1ull << lane) - 1ull));
    if (lane == 0) scan[wvi] = __popcll(m);
    __syncthreads();
    int woff = 0;
    #pragma unroll
    for (int i = 0; i < 4; ++i) if (i < wvi) woff += scan[i];
    const int tot = scan[0] + scan[1] + scan[2] + scan[3];
    if (act) idx[e * N_TOK + base + woff + pre] = n;
    __syncthreads();
    if (threadIdx.x == 0) base += tot;
    __syncthreads();
  }
  const int M = base;
  if (threadIdx.x == 0) cnt[e] = M;
  const int Mpad = (M + 255) & ~255;
  for (int i = M + threadIdx.x; i < Mpad; i += 256) idx[e * N_TOK + i] = 0;
}

// =======================================================================
// GEMM1: fused gate+up on COMPACTED tokens, 256x64 tile, BK=64, pipelined
// (A 3-slot, B 2-slot), T2 swizzle, counted vmcnt(4).
// Epilogue silu(g)*u*w scattered to original A2 rows (bf16).
// =======================================================================
#define G1_PHASE(mq) do {                                                        \
    const char* Ab_ = As + sA * 32768 + (wr * 128 + (mq) * 64) * 128 + rb;       \
    const char* Bg_ = Bgs + sBr * 8192 + (wc * 16) * 128 + rb;                   \
    const char* Bu_ = Bus + sBr * 8192 + (wc * 16) * 128 + rb;                   \
    bf16x8 av_[4][2];                                                            \
    _Pragma("unroll")                                                            \
    for (int i = 0; i < 4; ++i) {                                                \
      av_[i][0] = *(const bf16x8*)(Ab_ + i * 2048 + cp0);                        \
      av_[i][1] = *(const bf16x8*)(Ab_ + i * 2048 + cp1);                        \
    }                                                                            \
    bf16x8 bg0_ = *(const bf16x8*)(Bg_ + cp0);                                   \
    bf16x8 bg1_ = *(const bf16x8*)(Bg_ + cp1);                                   \
    bf16x8 bu0_ = *(const bf16x8*)(Bu_ + cp0);                                   \
    bf16x8 bu1_ = *(const bf16x8*)(Bu_ + cp1);                                   \
    __builtin_amdgcn_s_setprio(1);                                               \
    _Pragma("unroll")                                                            \
    for (int i = 0; i < 4; ++i) {                                                \
      ag[(mq)*4+i] = __builtin_amdgcn_mfma_f32_16x16x32_bf16(av_[i][0], bg0_, ag[(mq)*4+i], 0,0,0); \
      au[(mq)*4+i] = __builtin_amdgcn_mfma_f32_16x16x32_bf16(av_[i][0], bu0_, au[(mq)*4+i], 0,0,0); \
      ag[(mq)*4+i] = __builtin_amdgcn_mfma_f32_16x16x32_bf16(av_[i][1], bg1_, ag[(mq)*4+i], 0,0,0); \
      au[(mq)*4+i] = __builtin_amdgcn_mfma_f32_16x16x32_bf16(av_[i][1], bu1_, au[(mq)*4+i], 0,0,0); \
    }                                                                            \
    __builtin_amdgcn_s_setprio(0);                                               \
  } while (0)

__global__ void __launch_bounds__(512, 2) k_gemm1(
    const unsigned short* __restrict__ xb,
    const unsigned short* __restrict__ Wg,
    const unsigned short* __restrict__ Wu,
    const float* __restrict__ w,
    const int* __restrict__ idx,
    const int* __restrict__ cnt,
    unsigned short* __restrict__ A2,
    int e0, int k2g, int nwg) {
  extern __shared__ char lds[];
  char* As  = lds;                  // 3 x 32768 = 98304
  char* Bgs = lds + 98304;          // 2 x 8192
  char* Bus = lds + 114688;         // 2 x 8192  (total 131072)
  const int tid = threadIdx.x;
  const int l = tid & 63, wv = tid >> 6;

  // XCD-chunk bijective swizzle; expert-major, 4f x 8y sub-chunks (B L2-resident)
  const int h = blockIdx.x;
  const int chunk = nwg >> 3;
  const int L = (h & 7) * chunk + (h >> 3);
  const int eloc = L >> 9;                 // 512 blocks/expert
  const int e = e0 + eloc;
  const int idxq = L & 511;                // 16 f-blocks x 32 y-blocks
  const int sub = idxq >> 5;               // 16 sub-chunks of 4f x 8y
  const int f = ((sub & 3) << 2) | ((idxq >> 3) & 3);
  const int y = ((sub >> 2) << 3) | (idxq & 7);
  const int bm = y << 8;                   // 256-row tile (compacted space)
  const int bf = f << 6;                   // 64-col f tile
  const int wr = wv >> 2, wc = wv & 3;     // 2M x 4N waves

  const int Me = cnt[e];
  if (bm >= Me) return;                    // bm multiple of 256: bm<Me <=> bm<Mpad
  const int* idxe = idx + e * N_TOK;

  const unsigned short* gBg = Wg + ((size_t)e * FF + bf) * HD;
  const unsigned short* gBu = Wu + ((size_t)e * FF + bf) * HD;

  // staging: pre-swizzled global source, linear LDS dest (rule #21)
  const int sr8  = l >> 3;
  const int scol = ((l & 7) ^ sr8) << 3;   // elements
  // frag reads: same involution on the read side
  const int fr  = l & 15;
  const int rb  = fr << 7;                 // row byte (128B rows)
  const int kc  = (l >> 4) << 4;
  const int swz = (l & 7) << 4;
  const int cp0 = kc ^ swz;
  const int cp1 = (64 + kc) ^ swz;

  // per-thread A row base pointers (gathered via compacted index; block-constant)
  const unsigned short* aP[4];
  #pragma unroll
  for (int c = 0; c < 4; ++c)
    aP[c] = xb + (size_t)idxe[bm + (c * 8 + wv) * 8 + sr8] * HD + scol;

  f32x4 ag[8], au[8];
  const f32x4 zero = {0.f, 0.f, 0.f, 0.f};
  #pragma unroll
  for (int i = 0; i < 8; ++i) { ag[i] = zero; au[i] = zero; }

  // prologue: A(0), B(0), A(1); leave A(1)'s 4 loads in flight
  stage256i(aP, 0, As, wv);
  stage64(gBg, HD, 0, Bgs, wv, sr8, scol);
  stage64(gBu, HD, 0, Bus, wv, sr8, scol);
  stage256i(aP, 64, As + 32768, wv);
  asm volatile("s_waitcnt vmcnt(4)" ::: "memory");
  __builtin_amdgcn_s_barrier();
  __builtin_amdgcn_sched_barrier(0);

  const int NT = HD / 64;   // 32
  int sA = 0;               // A read slot (t % 3)
  for (int t = 0; t < NT; ++t) {
    const int tB = (t + 1 < NT) ? t + 1 : NT - 1;
    const int tA = (t + 2 < NT) ? t + 2 : NT - 1;
    const int sBw = (t + 1) & 1;
    const int sBr = t & 1;
    const int sAw = (sA >= 1) ? sA - 1 : 2;   // (sA+2)%3
    stage64(gBg, HD, tB * 64, Bgs + sBw * 8192, wv, sr8, scol);
    stage64(gBu, HD, tB * 64, Bus + sBw * 8192, wv, sr8, scol);
    G1_PHASE(0);
    stage256i(aP, tA * 64, As + sAw * 32768, wv);
    G1_PHASE(1);
    asm volatile("s_waitcnt vmcnt(4)" ::: "memory");  // keep A(t+2) in flight
    __builtin_amdgcn_s_barrier();
    __builtin_amdgcn_sched_barrier(0);
    sA = (sA == 2) ? 0 : sA + 1;
  }

  // epilogue: silu(g)*u*w -> A2 bf16, scattered to original token rows.
  // Padded rows (idx==0) write token0's exact value (bitwise-identical dup) or 0.
  const int orow = (l >> 4) << 2;
  #pragma unroll
  for (int am = 0; am < 8; ++am) {
    #pragma unroll
    for (int rr = 0; rr < 4; ++rr) {
      const int cm = bm + wr * 128 + am * 16 + orow + rr;
      const int n = idxe[cm];
      const float wn = w[n * 8 + e];
      const float g = ag[am][rr];
      const float u = au[am][rr];
      const float s = g / (1.f + __expf(-g));
      A2[(size_t)n * k2g + (size_t)eloc * FF + bf + wc * 16 + fr] = f2bf(s * u * wn);
    }
  }
}

// =======================================================================
// GEMM2: out(+)= A2 @ Wd, 256x128 tile, BK=64, same pipeline structure.
// =======================================================================
#define G2_PHASE(mq) do {                                                        \
    const char* Ab_ = As + sA * 32768 + (wr * 128 + (mq) * 64) * 128 + rb;       \
    const char* Bb_ = Bs + sBr * 16384 + (wc * 32) * 128 + rb;                   \
    bf16x8 av_[4][2];                                                            \
    bf16x8 bv_[2][2];                                                            \
    _Pragma("unroll")                                                            \
    for (int i = 0; i < 4; ++i) {                                                \
      av_[i][0] = *(const bf16x8*)(Ab_ + i * 2048 + cp0);                        \
      av_[i][1] = *(const bf16x8*)(Ab_ + i * 2048 + cp1);                        \
    }                                                                            \
    _Pragma("unroll")                                                            \
    for (int j = 0; j < 2; ++j) {                                                \
      bv_[j][0] = *(const bf16x8*)(Bb_ + j * 2048 + cp0);                        \
      bv_[j][1] = *(const bf16x8*)(Bb_ + j * 2048 + cp1);                        \
    }                                                                            \
    __builtin_amdgcn_s_setprio(1);                                               \
    _Pragma("unroll")                                                            \
    for (int i = 0; i < 4; ++i) {                                                \
      _Pragma("unroll")                                                          \
      for (int j = 0; j < 2; ++j) {                                              \
        acc[(mq)*4+i][j] = __builtin_amdgcn_mfma_f32_16x16x32_bf16(av_[i][0], bv_[j][0], acc[(mq)*4+i][j], 0,0,0); \
        acc[(mq)*4+i][j] = __builtin_amdgcn_mfma_f32_16x16x32_bf16(av_[i][1], bv_[j][1], acc[(mq)*4+i][j], 0,0,0); \
      }                                                                          \
    }                                                                            \
    __builtin_amdgcn_s_setprio(0);                                               \
  } while (0)

__global__ void __launch_bounds__(512, 2) k_gemm2(
    const unsigned short* __restrict__ A2,
    const unsigned short* __restrict__ Wd,
    float* __restrict__ out,
    int k2g, int accum) {
  extern __shared__ char lds[];
  char* As = lds;                   // 3 x 32768 = 98304
  char* Bs = lds + 98304;           // 2 x 16384 (total 131072)
  const int tid = threadIdx.x;
  const int l = tid & 63, wv = tid >> 6;

  const int h = blockIdx.x;
  const int L = (h & 7) * 64 + (h >> 3);   // grid 512
  const int y = L >> 4;                    // 32 m-blocks
  const int x = L & 15;                    // 16 n-blocks
  const int bm = y << 8;
  const int bn = x << 7;
  const int wr = wv >> 2, wc = wv & 3;

  const unsigned short* gA = A2 + (size_t)bm * k2g;
  const unsigned short* gB = Wd + (size_t)bn * (NE * FF);

  const int sr8  = l >> 3;
  const int scol = ((l & 7) ^ sr8) << 3;
  const int fr  = l & 15;
  const int rb  = fr << 7;
  const int kc  = (l >> 4) << 4;
  const int swz = (l & 7) << 4;
  const int cp0 = kc ^ swz;
  const int cp1 = (64 + kc) ^ swz;

  f32x4 acc[8][2];
  const f32x4 zero = {0.f, 0.f, 0.f, 0.f};
  #pragma unroll
  for (int i = 0; i < 8; ++i) { acc[i][0] = zero; acc[i][1] = zero; }

  stage256(gA, k2g, 0, As, wv, sr8, scol);
  stage128(gB, NE * FF, 0, Bs, wv, sr8, scol);
  stage256(gA, k2g, 64, As + 32768, wv, sr8, scol);
  asm volatile("s_waitcnt vmcnt(4)" ::: "memory");
  __builtin_amdgcn_s_barrier();
  __builtin_amdgcn_sched_barrier(0);

  const int NT = k2g / 64;
  int sA = 0;
  for (int t = 0; t < NT; ++t) {
    const int tB = (t + 1 < NT) ? t + 1 : NT - 1;
    const int tA = (t + 2 < NT) ? t + 2 : NT - 1;
    const int sBw = (t + 1) & 1;
    const int sBr = t & 1;
    const int sAw = (sA >= 1) ? sA - 1 : 2;
    stage128(gB, NE * FF, tB * 64, Bs + sBw * 16384, wv, sr8, scol);
    G2_PHASE(0);
    stage256(gA, k2g, tA * 64, As + sAw * 32768, wv, sr8, scol);
    G2_PHASE(1);
    asm volatile("s_waitcnt vmcnt(4)" ::: "memory");
    __builtin_amdgcn_s_barrier();
    __builtin_amdgcn_sched_barrier(0);
    sA = (sA == 2) ? 0 : sA + 1;
  }

  const int orow = (l >> 4) << 2;
  #pragma unroll
  for (int am = 0; am < 8; ++am) {
    #pragma unroll
    for (int rr = 0; rr < 4; ++rr) {
      const int n = bm + wr * 128 + am * 16 + orow + rr;
      float* op = out + (size_t)n * HD + bn + wc * 32 + fr;
      #pragma unroll
      for (int j = 0; j < 2; ++j) {
        const float v = acc[am][j][rr];
        op[j * 16] = accum ? (op[j * 16] + v) : v;
      }
    }
  }
}

extern "C" void kernel_launch(void* const* d_in, const int* in_sizes, int n_in,
                              void* d_out, int out_size, void* d_ws, size_t ws_size,
                              hipStream_t stream) {
  (void)in_sizes; (void)out_size;
  if (n_in < 5) return;
  const float* x  = (const float*)d_in[0];
  const float* Wr = (const float*)d_in[1];
  const float* Wg = (const float*)d_in[2];
  const float* Wu = (const float*)d_in[3];
  const float* Wd = (const float*)d_in[4];
  float* out  = (float*)d_out;
  float* rout = out + (size_t)N_TOK * HD;

  hipFuncSetAttribute((const void*)k_gemm1, hipFuncAttributeMaxDynamicSharedMemorySize, 131072);
  hipFuncSetAttribute((const void*)k_gemm2, hipFuncAttributeMaxDynamicSharedMemorySize, 131072);

  char* ws = (char*)d_ws;
  const size_t SZ_XB = (size_t)N_TOK * HD * 2;      // 33,554,432 B
  const size_t SZ_W  = (size_t)NE * HD * FF * 2;    // 33,554,432 B each
  unsigned short* xb    = (unsigned short*)(ws);
  unsigned short* Wg_bt = (unsigned short*)(ws + SZ_XB);
  unsigned short* Wu_bt = (unsigned short*)(ws + SZ_XB + SZ_W);
  unsigned short* Wd_bt = (unsigned short*)(ws + SZ_XB + 2 * SZ_W);
  float*          wbuf  = (float*)(ws + SZ_XB + 3 * SZ_W);
  size_t off = SZ_XB + 3 * SZ_W + (size_t)N_TOK * NE * 4;
  int* idxbuf = (int*)(ws + off);  off += (size_t)NE * N_TOK * 4;   // 256 KB
  int* cntbuf = (int*)(ws + off);  off += 256;
  const size_t fixed = off;
  unsigned short* A2 = (unsigned short*)(ws + fixed);

  const size_t perE = (size_t)N_TOK * FF * 2;       // 16,777,216 B per expert slab
  int G = 8;
  while (G > 1 && fixed + (size_t)G * perE > ws_size) G >>= 1;

  // weight transposes (fp32 -> bf16 B^T layouts)
  dim3 tb(32, 8);
  k_tconv<<<dim3(FF / 32, HD / 32, NE), tb, 0, stream>>>(
      Wg, Wg_bt, HD, FF, (size_t)HD * FF, (size_t)FF * HD, (size_t)HD);
  k_tconv<<<dim3(FF / 32, HD / 32, NE), tb, 0, stream>>>(
      Wu, Wu_bt, HD, FF, (size_t)HD * FF, (size_t)FF * HD, (size_t)HD);
  k_tconv<<<dim3(HD / 32, FF / 32, NE), tb, 0, stream>>>(
      Wd, Wd_bt, FF, HD, (size_t)FF * HD, (size_t)FF, (size_t)(NE * FF));

  // router (fp32 exact) -> wbuf + d_out router section; also emits xb (bf16)
  k_router<<<N_TOK / 4, 256, 0, stream>>>(x, Wr, wbuf, rout, xb);

  // per-expert token compaction
  k_compact<<<NE, 256, 0, stream>>>(wbuf, idxbuf, cntbuf);

  // expert GEMMs (G experts per pass; accumulate across passes)
  const int k2g = G * FF;
  for (int e0 = 0; e0 < NE; e0 += G) {
    hipMemsetAsync(A2, 0, (size_t)G * perE, stream);   // zero inactive rows
    const int nwg1 = 512 * G;   // 16f x 32y per expert (static; blocks past Me exit)
    k_gemm1<<<nwg1, 512, 131072, stream>>>(xb, Wg_bt, Wu_bt, wbuf, idxbuf, cntbuf,
                                           A2, e0, k2g, nwg1);
    k_gemm2<<<512, 512, 131072, stream>>>(A2, Wd_bt + (size_t)e0 * FF, out, k2g, e0 != 0);
  }
}